// Round 1
// baseline (593.197 us; speedup 1.0000x reference)
//
#include <hip/hip_runtime.h>

// Problem constants (fixed by the reference)
#define BB 16
#define NN 1000
#define DD 256
#define LL 3
#define MAXNZ 256           // per-row off-diagonal capacity (mean ~40, std ~6 -> 256 is >30 sigma)
#define MROWS (BB * NN)     // 16000

// ---------------------------------------------------------------------------
// Kernel 1: build sparse structure of A = prot_contacts + eye (layer-invariant)
// One wave per row, ordered append via ballot+prefix (deterministic).
// ---------------------------------------------------------------------------
__global__ __launch_bounds__(256) void build_sparse(
    const float* __restrict__ contacts,
    int* __restrict__ idx, int* __restrict__ cnt, float* __restrict__ adiag)
{
    int wave = (int)((blockIdx.x * blockDim.x + threadIdx.x) >> 6);
    int lane = threadIdx.x & 63;
    if (wave >= MROWS) return;
    int b = wave / NN;
    int i = wave - b * NN;
    const float* row = contacts + (size_t)b * NN * NN + (size_t)i * NN;
    int* out = idx + (size_t)wave * MAXNZ;
    int count = 0;
    for (int j0 = 0; j0 < NN; j0 += 64) {
        int j = j0 + lane;
        float v = (j < NN) ? row[j] : 0.0f;
        bool p = (v != 0.0f) && (j != i);
        unsigned long long bal = __ballot(p);
        if (p) {
            int pre = __popcll(bal & ((1ull << lane) - 1ull));
            out[count + pre] = j;
        }
        count += __popcll(bal);
    }
    if (lane == 0) {
        cnt[wave] = count;
        adiag[wave] = row[i] + 1.0f;   // diagonal of A: pc_ii + 1 (can be 2.0!)
    }
}

// ---------------------------------------------------------------------------
// Kernel 2: sparse attention + aggregate.
// x1[b,i,:] = sum_j s_ij x0[b,j,:] / sum_j s_ij, over nonzeros of A row i.
// One wave per row; lane holds 4 consecutive dims (float4).
// ---------------------------------------------------------------------------
__global__ __launch_bounds__(256) void sparse_agg(
    const float* __restrict__ y,   // x0 @ W_l  [16000,256]
    const float* __restrict__ x0,  // [16000,256]
    const int* __restrict__ idx, const int* __restrict__ cnt,
    const float* __restrict__ adiag, float* __restrict__ xout)
{
    int wave = (int)((blockIdx.x * blockDim.x + threadIdx.x) >> 6);
    int lane = threadIdx.x & 63;
    if (wave >= MROWS) return;
    int b = wave / NN;
    const float4 y4  = *(const float4*)(y  + (size_t)wave * DD + lane * 4);
    const float4 xi4 = *(const float4*)(x0 + (size_t)wave * DD + lane * 4);
    const float* xb = x0 + (size_t)b * NN * DD;

    // diagonal term: (exp(s_ii) + 1e-5) * adiag
    float p = y4.x * xi4.x + y4.y * xi4.y + y4.z * xi4.z + y4.w * xi4.w;
    #pragma unroll
    for (int m = 32; m; m >>= 1) p += __shfl_xor(p, m);
    float wd = (__expf(p) + 1e-5f) * adiag[wave];
    float denom = wd;
    float4 acc = make_float4(wd * xi4.x, wd * xi4.y, wd * xi4.z, wd * xi4.w);

    int c = cnt[wave];
    const int* ip = idx + (size_t)wave * MAXNZ;
    for (int k = 0; k < c; ++k) {
        int j = ip[k];
        float4 xj = *(const float4*)(xb + (size_t)j * DD + lane * 4);
        float q = y4.x * xj.x + y4.y * xj.y + y4.z * xj.z + y4.w * xj.w;
        #pragma unroll
        for (int m = 32; m; m >>= 1) q += __shfl_xor(q, m);
        float w = __expf(q);
        denom += w;
        acc.x += w * xj.x; acc.y += w * xj.y; acc.z += w * xj.z; acc.w += w * xj.w;
    }
    float inv = 1.0f / denom;
    *(float4*)(xout + (size_t)wave * DD + lane * 4) =
        make_float4(acc.x * inv, acc.y * inv, acc.z * inv, acc.w * inv);
}

// ---------------------------------------------------------------------------
// Kernel 3: fused GEMM  C[M,256] = op(A[M,256] @ W[256,256] + bias [+ skip])
// 64x64 tile, BK=16, 4x4 per thread, fp32 vector ALU.
// ---------------------------------------------------------------------------
__global__ __launch_bounds__(256) void gemm_fused(
    const float* __restrict__ A, const float* __restrict__ W,
    const float* __restrict__ bias, const float* __restrict__ skip,
    float* __restrict__ C, int relu)
{
    __shared__ float As[16][68];   // [k][m], padded
    __shared__ float Ws[16][64];   // [k][n]
    int tid = threadIdx.x;
    int tx = tid & 15, ty = tid >> 4;
    int mBase = blockIdx.y * 64;
    int nBase = blockIdx.x * 64;

    float acc[4][4] = {};

    int am = tid >> 2;           // 0..63 row within tile
    int ak = (tid & 3) * 4;      // k offset 0,4,8,12
    int wk = tid >> 4;           // 0..15 k row
    int wn = (tid & 15) * 4;     // n offset
    const float* Ag = A + (size_t)(mBase + am) * 256 + ak;
    const float* Wg = W + (size_t)wk * 256 + nBase + wn;

    for (int kb = 0; kb < 256; kb += 16) {
        float4 av = *(const float4*)(Ag + kb);
        float4 wv = *(const float4*)(Wg + (size_t)kb * 256);
        __syncthreads();
        As[ak + 0][am] = av.x; As[ak + 1][am] = av.y;
        As[ak + 2][am] = av.z; As[ak + 3][am] = av.w;
        *(float4*)&Ws[wk][wn] = wv;
        __syncthreads();
        #pragma unroll
        for (int k = 0; k < 16; ++k) {
            float4 a4 = *(const float4*)&As[k][ty * 4];
            float4 w4 = *(const float4*)&Ws[k][tx * 4];
            float am_[4] = {a4.x, a4.y, a4.z, a4.w};
            float wn_[4] = {w4.x, w4.y, w4.z, w4.w};
            #pragma unroll
            for (int i2 = 0; i2 < 4; ++i2)
                #pragma unroll
                for (int j2 = 0; j2 < 4; ++j2)
                    acc[i2][j2] = fmaf(am_[i2], wn_[j2], acc[i2][j2]);
        }
    }

    float4 bv = make_float4(0.f, 0.f, 0.f, 0.f);
    if (bias) bv = *(const float4*)(bias + nBase + tx * 4);
    #pragma unroll
    for (int i2 = 0; i2 < 4; ++i2) {
        int m = mBase + ty * 4 + i2;
        float4 o = make_float4(acc[i2][0] + bv.x, acc[i2][1] + bv.y,
                               acc[i2][2] + bv.z, acc[i2][3] + bv.w);
        if (relu) {
            o.x = fmaxf(o.x, 0.f); o.y = fmaxf(o.y, 0.f);
            o.z = fmaxf(o.z, 0.f); o.w = fmaxf(o.w, 0.f);
        }
        if (skip) {
            float4 s4 = *(const float4*)(skip + (size_t)m * 256 + nBase + tx * 4);
            o.x += s4.x; o.y += s4.y; o.z += s4.z; o.w += s4.w;
        }
        *(float4*)(C + (size_t)m * 256 + nBase + tx * 4) = o;
    }
}

// ---------------------------------------------------------------------------
extern "C" void kernel_launch(void* const* d_in, const int* in_sizes, int n_in,
                              void* d_out, int out_size, void* d_ws, size_t ws_size,
                              hipStream_t stream)
{
    const float* x_in     = (const float*)d_in[0];  // [16,1000,256]
    const float* contacts = (const float*)d_in[1];  // [16,1000,1000]
    const float* W_list   = (const float*)d_in[2];  // [3,256,256]
    const float* dense_W  = (const float*)d_in[3];  // [3,2,256,256]
    const float* dense_b  = (const float*)d_in[4];  // [3,2,256]
    const float* final_W  = (const float*)d_in[5];  // [256,256]
    const float* final_b  = (const float*)d_in[6];  // [256]
    float* out = (float*)d_out;

    char* ws = (char*)d_ws;
    const size_t bufBytes = (size_t)MROWS * DD * sizeof(float);   // 16.384 MB
    float* bufA = (float*)(ws);
    float* bufB = (float*)(ws + bufBytes);
    float* bufC = (float*)(ws + 2 * bufBytes);
    int*   idx  = (int*)(ws + 3 * bufBytes);
    int*   cnt  = (int*)(ws + 3 * bufBytes + (size_t)MROWS * MAXNZ * sizeof(int));
    float* adiag = (float*)((char*)cnt + (size_t)MROWS * sizeof(int));
    // total ws use: ~65.7 MB

    // Sparse structure (layer-invariant, rebuilt each call for determinism)
    build_sparse<<<MROWS / 4, 256, 0, stream>>>(contacts, idx, cnt, adiag);

    dim3 ggrid(DD / 64, MROWS / 64);   // (4, 250)
    const float* curx = x_in;
    for (int l = 0; l < LL; ++l) {
        float* yv = bufA;
        float* ov = (l == 1) ? bufC : bufB;
        // y = x0 @ W_l
        gemm_fused<<<ggrid, 256, 0, stream>>>(curx, W_list + (size_t)l * 65536,
                                              nullptr, nullptr, yv, 0);
        // x1 = row-normalized sparse attention aggregate
        sparse_agg<<<MROWS / 4, 256, 0, stream>>>(yv, curx, idx, cnt, adiag, ov);
        // dense 1 (relu)
        gemm_fused<<<ggrid, 256, 0, stream>>>(ov, dense_W + (size_t)(l * 2 + 0) * 65536,
                                              dense_b + (size_t)(l * 2 + 0) * 256,
                                              nullptr, yv, 1);
        // dense 2 (relu) + skip(x0)
        gemm_fused<<<ggrid, 256, 0, stream>>>(yv, dense_W + (size_t)(l * 2 + 1) * 65536,
                                              dense_b + (size_t)(l * 2 + 1) * 256,
                                              curx, ov, 1);
        curx = ov;
    }
    // final projection
    gemm_fused<<<ggrid, 256, 0, stream>>>(curx, final_W, final_b, nullptr, out, 0);
}

// Round 2
// 503.446 us; speedup vs baseline: 1.1783x; 1.1783x over previous
//
#include <hip/hip_runtime.h>

#define BB 16
#define NN 1000
#define DD 256
#define LL 3
#define MAXNZ 256
#define MROWS (BB * NN)

// ---------------------------------------------------------------------------
// Kernel 1: build sparse structure of A = prot_contacts + eye (layer-invariant)
// ---------------------------------------------------------------------------
__global__ __launch_bounds__(256) void build_sparse(
    const float* __restrict__ contacts,
    int* __restrict__ idx, int* __restrict__ cnt, float* __restrict__ adiag)
{
    int wave = (int)((blockIdx.x * blockDim.x + threadIdx.x) >> 6);
    int lane = threadIdx.x & 63;
    if (wave >= MROWS) return;
    int b = wave / NN;
    int i = wave - b * NN;
    const float* row = contacts + (size_t)b * NN * NN + (size_t)i * NN;
    int* out = idx + (size_t)wave * MAXNZ;
    int count = 0;
    for (int j0 = 0; j0 < NN; j0 += 64) {
        int j = j0 + lane;
        float v = (j < NN) ? row[j] : 0.0f;
        bool p = (v != 0.0f) && (j != i);
        unsigned long long bal = __ballot(p);
        if (p) {
            int pre = __popcll(bal & ((1ull << lane) - 1ull));
            out[count + pre] = j;
        }
        count += __popcll(bal);
    }
    if (lane == 0) {
        cnt[wave] = count;
        adiag[wave] = row[i] + 1.0f;
    }
}

// ---------------------------------------------------------------------------
// Kernel 2: sparse attention aggregate, ILP-unrolled by 8.
// ---------------------------------------------------------------------------
__global__ __launch_bounds__(256) void sparse_agg(
    const float* __restrict__ y, const float* __restrict__ x0,
    const int* __restrict__ idx, const int* __restrict__ cnt,
    const float* __restrict__ adiag, float* __restrict__ xout)
{
    int wv = (int)((blockIdx.x * blockDim.x + threadIdx.x) >> 6);
    int lane = threadIdx.x & 63;
    if (wv >= MROWS) return;
    int row = __builtin_amdgcn_readfirstlane(wv);   // wave-uniform -> scalar addressing
    int b = row / NN;
    const float4 y4  = *(const float4*)(y  + (size_t)row * DD + lane * 4);
    const float4 xi4 = *(const float4*)(x0 + (size_t)row * DD + lane * 4);
    const float* xb = x0 + (size_t)b * NN * DD;

    // diagonal: (exp(s_ii) + 1e-5) * (pc_ii + 1)
    float p = y4.x * xi4.x + y4.y * xi4.y + y4.z * xi4.z + y4.w * xi4.w;
    #pragma unroll
    for (int m = 32; m; m >>= 1) p += __shfl_xor(p, m);
    float wd = (__expf(p) + 1e-5f) * adiag[row];
    float denom = wd;
    float4 acc = make_float4(wd * xi4.x, wd * xi4.y, wd * xi4.z, wd * xi4.w);

    const int c = cnt[row];
    const int* ip = idx + (size_t)row * MAXNZ;
    int k = 0;
    for (; k + 8 <= c; k += 8) {
        int4 ja = *(const int4*)(ip + k);
        int4 jb = *(const int4*)(ip + k + 4);
        int jj[8] = {ja.x, ja.y, ja.z, ja.w, jb.x, jb.y, jb.z, jb.w};
        float4 xv[8];
        #pragma unroll
        for (int u = 0; u < 8; ++u)
            xv[u] = *(const float4*)(xb + (size_t)jj[u] * DD + lane * 4);
        float q[8];
        #pragma unroll
        for (int u = 0; u < 8; ++u)
            q[u] = y4.x * xv[u].x + y4.y * xv[u].y + y4.z * xv[u].z + y4.w * xv[u].w;
        #pragma unroll
        for (int m = 32; m; m >>= 1) {
            #pragma unroll
            for (int u = 0; u < 8; ++u) q[u] += __shfl_xor(q[u], m);
        }
        #pragma unroll
        for (int u = 0; u < 8; ++u) {
            float w = __expf(q[u]);
            denom += w;
            acc.x += w * xv[u].x; acc.y += w * xv[u].y;
            acc.z += w * xv[u].z; acc.w += w * xv[u].w;
        }
    }
    for (; k < c; ++k) {
        int j = ip[k];
        float4 xj = *(const float4*)(xb + (size_t)j * DD + lane * 4);
        float q = y4.x * xj.x + y4.y * xj.y + y4.z * xj.z + y4.w * xj.w;
        #pragma unroll
        for (int m = 32; m; m >>= 1) q += __shfl_xor(q, m);
        float w = __expf(q);
        denom += w;
        acc.x += w * xj.x; acc.y += w * xj.y; acc.z += w * xj.z; acc.w += w * xj.w;
    }
    float inv = 1.0f / denom;
    *(float4*)(xout + (size_t)row * DD + lane * 4) =
        make_float4(acc.x * inv, acc.y * inv, acc.z * inv, acc.w * inv);
}

// ---------------------------------------------------------------------------
// Kernel 3: fused GEMM  C[M,256] = op(A[M,256] @ W[256,256] + bias [+ skip])
// 64x64 tile, BK=32 (8 staging rounds), 4x4 per thread, fp32 vector ALU.
// All LDS patterns verified <=2-way bank aliasing.
// ---------------------------------------------------------------------------
__global__ __launch_bounds__(256) void gemm_fused(
    const float* __restrict__ A, const float* __restrict__ W,
    const float* __restrict__ bias, const float* __restrict__ skip,
    float* __restrict__ C, int relu)
{
    __shared__ float As[32][68];   // [k][m]
    __shared__ float Ws[32][68];   // [k][n]
    int tid = threadIdx.x;
    int tx = tid & 15, ty = tid >> 4;
    int mBase = blockIdx.y * 64;
    int nBase = blockIdx.x * 64;

    float acc[4][4] = {};

    int am = tid >> 2;           // 0..63 row within tile
    int ak = (tid & 3) * 4;      // k offset 0,4,8,12 (+16 for 2nd chunk)
    int wk = tid >> 3;           // 0..31 k row
    int wn = (tid & 7) * 8;      // n offset 0..56
    const float* Ag = A + (size_t)(mBase + am) * 256 + ak;
    const float* Wg = W + (size_t)wk * 256 + nBase + wn;

    for (int kb = 0; kb < 256; kb += 32) {
        float4 a0 = *(const float4*)(Ag + kb);
        float4 a1 = *(const float4*)(Ag + kb + 16);
        float4 w0 = *(const float4*)(Wg + (size_t)kb * 256);
        float4 w1 = *(const float4*)(Wg + (size_t)kb * 256 + 4);
        __syncthreads();
        As[ak + 0][am] = a0.x; As[ak + 1][am] = a0.y;
        As[ak + 2][am] = a0.z; As[ak + 3][am] = a0.w;
        As[ak + 16][am] = a1.x; As[ak + 17][am] = a1.y;
        As[ak + 18][am] = a1.z; As[ak + 19][am] = a1.w;
        *(float4*)&Ws[wk][wn] = w0;
        *(float4*)&Ws[wk][wn + 4] = w1;
        __syncthreads();
        #pragma unroll
        for (int k = 0; k < 32; ++k) {
            float4 a4 = *(const float4*)&As[k][ty * 4];
            float4 w4 = *(const float4*)&Ws[k][tx * 4];
            float am_[4] = {a4.x, a4.y, a4.z, a4.w};
            float wn_[4] = {w4.x, w4.y, w4.z, w4.w};
            #pragma unroll
            for (int i2 = 0; i2 < 4; ++i2)
                #pragma unroll
                for (int j2 = 0; j2 < 4; ++j2)
                    acc[i2][j2] = fmaf(am_[i2], wn_[j2], acc[i2][j2]);
        }
    }

    float4 bv = make_float4(0.f, 0.f, 0.f, 0.f);
    if (bias) bv = *(const float4*)(bias + nBase + tx * 4);
    #pragma unroll
    for (int i2 = 0; i2 < 4; ++i2) {
        int m = mBase + ty * 4 + i2;
        float4 o = make_float4(acc[i2][0] + bv.x, acc[i2][1] + bv.y,
                               acc[i2][2] + bv.z, acc[i2][3] + bv.w);
        if (relu) {
            o.x = fmaxf(o.x, 0.f); o.y = fmaxf(o.y, 0.f);
            o.z = fmaxf(o.z, 0.f); o.w = fmaxf(o.w, 0.f);
        }
        if (skip) {
            float4 s4 = *(const float4*)(skip + (size_t)m * 256 + nBase + tx * 4);
            o.x += s4.x; o.y += s4.y; o.z += s4.z; o.w += s4.w;
        }
        *(float4*)(C + (size_t)m * 256 + nBase + tx * 4) = o;
    }
}

// ---------------------------------------------------------------------------
extern "C" void kernel_launch(void* const* d_in, const int* in_sizes, int n_in,
                              void* d_out, int out_size, void* d_ws, size_t ws_size,
                              hipStream_t stream)
{
    const float* x_in     = (const float*)d_in[0];
    const float* contacts = (const float*)d_in[1];
    const float* W_list   = (const float*)d_in[2];
    const float* dense_W  = (const float*)d_in[3];
    const float* dense_b  = (const float*)d_in[4];
    const float* final_W  = (const float*)d_in[5];
    const float* final_b  = (const float*)d_in[6];
    float* out = (float*)d_out;

    char* ws = (char*)d_ws;
    const size_t bufBytes = (size_t)MROWS * DD * sizeof(float);
    float* bufA = (float*)(ws);
    float* bufB = (float*)(ws + bufBytes);
    float* bufC = (float*)(ws + 2 * bufBytes);
    int*   idx  = (int*)(ws + 3 * bufBytes);
    int*   cnt  = (int*)(ws + 3 * bufBytes + (size_t)MROWS * MAXNZ * sizeof(int));
    float* adiag = (float*)((char*)cnt + (size_t)MROWS * sizeof(int));

    build_sparse<<<MROWS / 4, 256, 0, stream>>>(contacts, idx, cnt, adiag);

    dim3 ggrid(DD / 64, MROWS / 64);   // (4, 250)
    const float* curx = x_in;
    for (int l = 0; l < LL; ++l) {
        float* yv = bufA;
        float* ov = (l == 1) ? bufC : bufB;
        gemm_fused<<<ggrid, 256, 0, stream>>>(curx, W_list + (size_t)l * 65536,
                                              nullptr, nullptr, yv, 0);
        sparse_agg<<<MROWS / 4, 256, 0, stream>>>(yv, curx, idx, cnt, adiag, ov);
        gemm_fused<<<ggrid, 256, 0, stream>>>(ov, dense_W + (size_t)(l * 2 + 0) * 65536,
                                              dense_b + (size_t)(l * 2 + 0) * 256,
                                              nullptr, yv, 1);
        gemm_fused<<<ggrid, 256, 0, stream>>>(yv, dense_W + (size_t)(l * 2 + 1) * 65536,
                                              dense_b + (size_t)(l * 2 + 1) * 256,
                                              curx, ov, 1);
        curx = ov;
    }
    gemm_fused<<<ggrid, 256, 0, stream>>>(curx, final_W, final_b, nullptr, out, 0);
}